// Round 3
// baseline (630.490 us; speedup 1.0000x reference)
//
#include <hip/hip_runtime.h>
#include <math.h>

#define B_ 1024
#define D_ 1024
#define N_ 128
#define PT_ 28
#define KSEL 32            // softmax over top 32 (k=33, last dropped)
#define NOISE_EPS_ 0.01f

typedef float fx4 __attribute__((ext_vector_type(4)));   // native vec for nt-store

// ---------------- Kernel 1a: unique t_embed rows ue[28][1024] (fp32) ---------
// grid (28, 8) x 256 threads (4 waves). Block (s, y) computes 128 outputs
// ue[s][y*128 .. y*128+127] via wave-wide coalesced dot products.
__global__ __launch_bounds__(256) void embed_kernel(
    const float* __restrict__ w1, const float* __restrict__ b1,
    const float* __restrict__ w2, const float* __restrict__ b2,
    float* __restrict__ ue)
{
    __shared__ __align__(16) float h[D_];
    const int s = blockIdx.x;
    const int tid = threadIdx.x;
    const float sf = (float)s;
    for (int d = tid; d < D_; d += 256) {
        float x = sf * w1[d] + b1[d];          // t @ w1.T + b1  (w1 is [D,1])
        h[d] = x / (1.0f + expf(-x));          // SiLU
    }
    __syncthreads();
    const int wave = tid >> 6;
    const int lane = tid & 63;
    const fx4* __restrict__ h4 = (const fx4*)h;
    for (int j = 0; j < 32; ++j) {
        const int i = blockIdx.y * 128 + wave * 32 + j;
        const fx4* __restrict__ row = (const fx4*)(w2 + (size_t)i * D_);
        float acc = 0.0f;
        #pragma unroll
        for (int k = 0; k < 4; ++k) {
            fx4 u  = row[k * 64 + lane];
            fx4 hv = h4 [k * 64 + lane];
            acc += u.x * hv.x + u.y * hv.y + u.z * hv.z + u.w * hv.w;
        }
        #pragma unroll
        for (int off = 32; off; off >>= 1) acc += __shfl_down(acc, off, 64);
        if (lane == 0) ue[(size_t)s * D_ + i] = acc + b2[i];
    }
}

// ------- Kernel 1b: unique clean logits + noise_std, uclean/unstd[28][128] ---
__global__ __launch_bounds__(256) void gate_precompute_kernel(
    const float* __restrict__ gate_w, const float* __restrict__ gate_b,
    const float* __restrict__ w_noise, const int* __restrict__ timestep,
    const float* __restrict__ ue, float* __restrict__ uclean, float* __restrict__ unstd)
{
    __shared__ __align__(16) float te[D_];
    __shared__ float pcl[N_];
    __shared__ float pnz[2][N_];
    const int s = blockIdx.x;
    const int tid = threadIdx.x;
    for (int d = tid; d < D_; d += 256) te[d] = ue[(size_t)s * D_ + d];
    __syncthreads();
    const int wave = tid >> 6;
    const int lane = tid & 63;

    for (int j = 0; j < 32; ++j) {
        const int n = wave * 32 + j;
        const float* __restrict__ grow = gate_w + (size_t)n * (D_ + 1);
        float acc = 0.0f;
        #pragma unroll
        for (int k = 0; k < 16; ++k)
            acc += grow[k * 64 + lane] * te[k * 64 + lane];
        #pragma unroll
        for (int off = 32; off; off >>= 1) acc += __shfl_down(acc, off, 64);
        if (lane == 0) pcl[n] = acc;
    }

    {
        const int n = (wave & 1) * 64 + lane;
        const int dbase = (wave >> 1) * 512;
        float acc = 0.0f;
        for (int d = 0; d < 512; ++d)
            acc += te[dbase + d] * w_noise[(size_t)(dbase + d) * N_ + n];
        pnz[wave >> 1][n] = acc;
    }
    __syncthreads();

    if (tid < N_) {
        const int step = timestep[0];
        float cl2 = pcl[tid]
                  + (float)step * gate_w[(size_t)tid * (D_ + 1) + D_]   // depth col
                  + gate_b[tid];
        uclean[s * N_ + tid] = cl2;
        float nz2 = pnz[0][tid] + pnz[1][tid];
        float sp = (nz2 > 20.0f) ? nz2 : log1pf(expf(nz2));   // softplus
        unstd[s * N_ + tid] = sp + NOISE_EPS_;
    }
}

// -------- Kernel 1c: per-row normalized gates[B][128] + out1 ----------------
// grid B_ x 128 threads. All gating math lives here so the streamer below
// is a pure store pipe.
__global__ __launch_bounds__(128) void gates_kernel(
    const float* __restrict__ noise, const int* __restrict__ timestep,
    const float* __restrict__ ue, const float* __restrict__ uclean,
    const float* __restrict__ unstd,
    float* __restrict__ gates_g, float* __restrict__ out1)
{
    __shared__ float noisy[N_];
    __shared__ float wsum[2];
    const int b = blockIdx.x;
    const int tid = threadIdx.x;
    const int tb = timestep[b];
    const float v = uclean[tb * N_ + tid]
                  + noise[(size_t)b * N_ + tid] * unstd[tb * N_ + tid];
    noisy[tid] = v;
    __syncthreads();
    int rank = 0; float mx = -INFINITY;
    for (int m = 0; m < N_; ++m) {
        float u = noisy[m];
        mx = fmaxf(mx, u);
        rank += ((u > v) || (u == v && m < tid)) ? 1 : 0;   // lax.top_k tie-break
    }
    float g = (rank < KSEL) ? expf(v - mx) : 0.0f;
    float s2 = g;
    #pragma unroll
    for (int off = 32; off; off >>= 1) s2 += __shfl_down(s2, off, 64);
    if ((tid & 63) == 0) wsum[tid >> 6] = s2;
    __syncthreads();
    const float inv = 1.0f / (wsum[0] + wsum[1]);
    gates_g[(size_t)b * N_ + tid] = g * inv;

    // out1: t_embed[b,:] = ue[tb,:]  (28 unique 4KB rows, L2-resident reads)
    const fx4* __restrict__ uer = (const fx4*)(ue + (size_t)tb * D_);
    fx4* __restrict__ o1 = (fx4*)(out1 + (size_t)b * D_);
    #pragma unroll
    for (int i = 0; i < 2; ++i)
        __builtin_nontemporal_store(uer[i * 128 + tid], o1 + i * 128 + tid);
}

// -------- Kernel 2: pure streaming masked-scale write -----------------------
// grid (B_, 4) x 256 threads (16 blocks/CU). Block (b,q) writes rows
// n in [q*32, q*32+32) of out0[b]. One sync, then branch-uniform nt stores.
__global__ __launch_bounds__(256) void out_kernel(
    const float* __restrict__ pe,     // [28,128,1024]
    const int* __restrict__ timestep,
    const float* __restrict__ gates_g,
    float* __restrict__ out0)
{
    __shared__ float sg[32];
    const int b = blockIdx.x, q = blockIdx.y;
    const int tid = threadIdx.x;
    const int step = timestep[0];
    if (tid < 32) sg[tid] = gates_g[(size_t)b * N_ + q * 32 + tid];
    __syncthreads();
    const fx4* __restrict__ psrc =
        (const fx4*)(pe + (size_t)step * N_ * D_) + (size_t)q * 32 * (D_ / 4);
    fx4* __restrict__ pdst =
        (fx4*)(out0 + (size_t)b * N_ * D_) + (size_t)q * 32 * (D_ / 4);
    #pragma unroll 4
    for (int it = 0; it < 32; ++it) {
        const float g = sg[it];                 // uniform across block
        const int idx = it * (D_ / 4) + tid;    // 256 fx4 per row
        fx4 o;
        if (g != 0.0f) o = psrc[idx] * g;
        else           o = (fx4)0.0f;
        __builtin_nontemporal_store(o, pdst + idx);
    }
}

extern "C" void kernel_launch(void* const* d_in, const int* in_sizes, int n_in,
                              void* d_out, int out_size, void* d_ws, size_t ws_size,
                              hipStream_t stream) {
    (void)in_sizes; (void)n_in; (void)out_size; (void)ws_size;
    const float* pe      = (const float*)d_in[0];
    const float* w1      = (const float*)d_in[1];
    const float* b1      = (const float*)d_in[2];
    const float* w2      = (const float*)d_in[3];
    const float* b2      = (const float*)d_in[4];
    const float* gate_w  = (const float*)d_in[5];
    const float* gate_b  = (const float*)d_in[6];
    const float* w_noise = (const float*)d_in[7];
    const float* noise   = (const float*)d_in[8];
    const int*   ts      = (const int*)d_in[9];

    float* ws      = (float*)d_ws;
    float* ue      = ws;                          // 28*1024 fp32
    float* uclean  = ue + PT_ * D_;               // 28*128
    float* unstd   = uclean + PT_ * N_;           // 28*128
    float* gates_g = unstd + PT_ * N_;            // 1024*128 (512 KiB)

    float* out0 = (float*)d_out;                       // [B,N,D]
    float* out1 = out0 + (size_t)B_ * N_ * D_;         // [B,D]

    hipLaunchKernelGGL(embed_kernel, dim3(PT_, 8), dim3(256), 0, stream,
                       w1, b1, w2, b2, ue);
    hipLaunchKernelGGL(gate_precompute_kernel, dim3(PT_), dim3(256), 0, stream,
                       gate_w, gate_b, w_noise, ts, ue, uclean, unstd);
    hipLaunchKernelGGL(gates_kernel, dim3(B_), dim3(128), 0, stream,
                       noise, ts, ue, uclean, unstd, gates_g, out1);
    hipLaunchKernelGGL(out_kernel, dim3(B_, 4), dim3(256), 0, stream,
                       pe, ts, gates_g, out0);
}